// Round 20
// baseline (307.573 us; speedup 1.0000x reference)
//
#include <hip/hip_runtime.h>
#include <float.h>
#include <math.h>

#define BB 64
#define NN 4096
#define EE 32768
#define FIN 12
#define HD 64
#define KK1 3277
#define KK2 2622
#define TBF 26    // ceil(KK1/128) -- 128-row tiles per graph for k_fuse
#define RB2 16    // blocks per graph for read2 partials

// ---------- CSR build: per-graph counting sort of edges by dst --------------
__global__ __launch_bounds__(1024) void k_csr(const int* __restrict__ ei,
    int* __restrict__ row_ofs, int* __restrict__ esrc, int g0) {
  __shared__ int cnt[NN];
  __shared__ int part[1024];
  int s = blockIdx.x, g = g0 + s, t = threadIdx.x;
  const int* src = ei + (size_t)g * 2 * EE;
  const int* dst = src + EE;
  for (int i = t; i < NN; i += 1024) cnt[i] = 0;
  __syncthreads();
  for (int e = t; e < EE; e += 1024) atomicAdd(&cnt[dst[e]], 1);
  __syncthreads();
  int c0 = cnt[t * 4], c1 = cnt[t * 4 + 1], c2 = cnt[t * 4 + 2], c3 = cnt[t * 4 + 3];
  int tot = c0 + c1 + c2 + c3;
  part[t] = tot;
  __syncthreads();
  for (int off = 1; off < 1024; off <<= 1) {
    int v = part[t];
    int add = (t >= off) ? part[t - off] : 0;
    __syncthreads();
    part[t] = v + add;
    __syncthreads();
  }
  int base = part[t] - tot;
  int b0 = base, b1 = base + c0, b2 = b1 + c1, b3 = b2 + c2;
  cnt[t * 4] = b0; cnt[t * 4 + 1] = b1; cnt[t * 4 + 2] = b2; cnt[t * 4 + 3] = b3;
  int* RO = row_ofs + (size_t)s * (NN + 1);
  RO[t * 4] = b0; RO[t * 4 + 1] = b1; RO[t * 4 + 2] = b2; RO[t * 4 + 3] = b3;
  if (t == 0) RO[NN] = EE;
  __syncthreads();
  int* ES = esrc + (size_t)s * EE;
  for (int e = t; e < EE; e += 1024) {
    int p = atomicAdd(&cnt[dst[e]], 1);
    ES[p] = src[e];
  }
}

// ---------- fused conv1 v3: W/b/p wave-uniform from global (scalarized) -----
__global__ __launch_bounds__(256, 4) void k_h1f(const float* __restrict__ x,
    const int* __restrict__ row_ofs, const int* __restrict__ esrc,
    const float* __restrict__ W1r, const float* __restrict__ b1,
    const float* __restrict__ W1n, const float* __restrict__ p1,
    float* __restrict__ h1, float* __restrict__ score1, int g0, int G8) {
  __shared__ float sCol[32][257];
  int tid = threadIdx.x;
  int b = blockIdx.x, s, nb;
  if (G8 > 0) { int hi = b >> 3; s = (b & 7) * G8 + hi / 16; nb = hi % 16; }
  else { s = b >> 4; nb = b & 15; }
  int node = nb * 256 + tid;
  int g = g0 + s;
  float nq = 0.f;
#pragma unroll 8
  for (int k = 0; k < 64; k++) nq += p1[k] * p1[k];
  float inv_norm = 1.0f / sqrtf(nq);
  const int* RO = row_ofs + (size_t)s * (NN + 1);
  const int* ES = esrc + (size_t)s * EE;
  const float4* X4 = (const float4*)(x + (size_t)g * NN * FIN);
  int r0 = RO[node], r1 = RO[node + 1];
  float a[FIN];
#pragma unroll
  for (int f = 0; f < FIN; f++) a[f] = 0.f;
  for (int i = r0; i < r1; i++) {
    int so = ES[i];
    float4 v0 = X4[(size_t)so * 3];
    float4 v1 = X4[(size_t)so * 3 + 1];
    float4 v2 = X4[(size_t)so * 3 + 2];
    a[0] += v0.x; a[1] += v0.y; a[2]  += v0.z; a[3]  += v0.w;
    a[4] += v1.x; a[5] += v1.y; a[6]  += v1.z; a[7]  += v1.w;
    a[8] += v2.x; a[9] += v2.y; a[10] += v2.z; a[11] += v2.w;
  }
  float xr[FIN];
  {
    float4 u0 = X4[(size_t)node * 3];
    float4 u1 = X4[(size_t)node * 3 + 1];
    float4 u2 = X4[(size_t)node * 3 + 2];
    xr[0] = u0.x; xr[1] = u0.y; xr[2]  = u0.z; xr[3]  = u0.w;
    xr[4] = u1.x; xr[5] = u1.y; xr[6]  = u1.z; xr[7]  = u1.w;
    xr[8] = u2.x; xr[9] = u2.y; xr[10] = u2.z; xr[11] = u2.w;
  }
  float* hbase = h1 + ((size_t)s * NN + (size_t)nb * 256) * HD;
  float v = 0.f;
  for (int half = 0; half < 2; half++) {
#pragma unroll 4
    for (int k0 = 0; k0 < 32; k0++) {
      int k = half * 32 + k0;
      const float* wr = &W1r[k * FIN];   // wave-uniform -> s_load
      const float* wn = &W1n[k * FIN];
      float acc = b1[k];
#pragma unroll
      for (int f = 0; f < FIN; f++) acc += a[f] * wr[f] + xr[f] * wn[f];
      acc = fmaxf(acc, 0.f);
      v += acc * p1[k];
      sCol[k0][tid] = acc;
    }
    __syncthreads();
    float* hb = hbase + half * 32;
    for (int i = tid; i < 256 * 32; i += 256) {
      int nd = i >> 5, c = i & 31;
      hb[(size_t)nd * HD + c] = sCol[c][nd];
    }
    __syncthreads();
  }
  score1[(size_t)s * NN + node] = v * inv_norm;
}

// ---------- top-k select via RADIX-SELECT (exact jax.lax.top_k SET) ---------
__global__ __launch_bounds__(1024) void k_select(const float* __restrict__ score,
    int scStride, int nvalid, int K, int* __restrict__ sel, int selStride,
    int* __restrict__ pos, int posStride, float* __restrict__ tgo) {
  __shared__ unsigned int keys[4096];
  __shared__ int hist[257];
  __shared__ int part[1024];
  __shared__ unsigned int sh_pref;
  __shared__ int sh_rem;
  int s = blockIdx.x, t = threadIdx.x;
  const float* sc = score + (size_t)s * scStride;
  for (int i = t; i < 4096; i += 1024) {
    unsigned int key = 0u;
    if (i < nvalid) {
      unsigned int bb = __float_as_uint(sc[i]);
      key = (bb & 0x80000000u) ? ~bb : (bb | 0x80000000u);  // order-preserving
    }
    keys[i] = key;
  }
  if (t == 0) { sh_pref = 0u; sh_rem = K; }
  __syncthreads();
  for (int sh = 24; sh >= 0; sh -= 8) {
    unsigned int pref = sh_pref;
    int rem = sh_rem;
    if (t < 256) hist[t] = 0;
    __syncthreads();
    for (int i = t; i < 4096; i += 1024) {
      unsigned int u = keys[i];
      bool in = (sh == 24) || ((u >> (sh + 8)) == pref);
      if (in) atomicAdd(&hist[(u >> sh) & 255], 1);
    }
    __syncthreads();
    for (int off = 1; off < 256; off <<= 1) {
      int v = 0;
      if (t < 256) { v = hist[t]; if (t + off < 256) v += hist[t + off]; }
      __syncthreads();
      if (t < 256) hist[t] = v;
      __syncthreads();
    }
    if (t < 256) {
      int ge = hist[t];
      int gt_ = (t == 255) ? 0 : hist[t + 1];
      if (ge >= rem && gt_ < rem) {
        sh_pref = (pref << 8) | (unsigned int)t;
        sh_rem = rem - gt_;
      }
    }
    __syncthreads();
  }
  unsigned int thr = sh_pref;
  int remEq = sh_rem;
  uint4 kk = *(const uint4*)&keys[4 * t];
  int eq0 = (kk.x == thr), eq1 = (kk.y == thr), eq2 = (kk.z == thr), eq3 = (kk.w == thr);
  int eqc = eq0 + eq1 + eq2 + eq3;
  part[t] = eqc;
  __syncthreads();
  for (int off = 1; off < 1024; off <<= 1) {
    int v = part[t];
    int add = (t >= off) ? part[t - off] : 0;
    __syncthreads();
    part[t] = v + add;
    __syncthreads();
  }
  int e_run = part[t] - eqc;
  int kp0 = (kk.x > thr) || (eq0 && (e_run < remEq)); e_run += eq0;
  int kp1 = (kk.y > thr) || (eq1 && (e_run < remEq)); e_run += eq1;
  int kp2 = (kk.z > thr) || (eq2 && (e_run < remEq)); e_run += eq2;
  int kp3 = (kk.w > thr) || (eq3 && (e_run < remEq));
  int kp[4] = {kp0, kp1, kp2, kp3};
  if (sel) {   // need ranks: second scan
    int kc = kp0 + kp1 + kp2 + kp3;
    __syncthreads();
    part[t] = kc;
    __syncthreads();
    for (int off = 1; off < 1024; off <<= 1) {
      int v = part[t];
      int add = (t >= off) ? part[t - off] : 0;
      __syncthreads();
      part[t] = v + add;
      __syncthreads();
    }
    int r = part[t] - kc;
#pragma unroll
    for (int q = 0; q < 4; q++) {
      int i = 4 * t + q;
      if (i < nvalid) {
        if (kp[q]) {
          sel[(size_t)s * selStride + r] = i;
          if (pos) pos[(size_t)s * posStride + i] = r;
          if (tgo) tgo[(size_t)s * NN + i] = tanhf(sc[i]);
        } else {
          if (pos) pos[(size_t)s * posStride + i] = -1;
          if (tgo) tgo[(size_t)s * NN + i] = 0.f;
        }
      }
      r += kp[q];
    }
  } else {     // flag-only fast path (stage 2)
#pragma unroll
    for (int q = 0; q < 4; q++) {
      int i = 4 * t + q;
      if (i < nvalid) {
        if (pos) pos[(size_t)s * posStride + i] = kp[q] ? 0 : -1;
        if (tgo) tgo[(size_t)s * NN + i] = kp[q] ? tanhf(sc[i]) : 0.f;
      }
    }
  }
}

// ---------- k_fuse v7: 128-row tiles + 8x4 register tile --------------------
// Amortizes per-row fixed costs (4 k-fuse archs all hit ~140us; R19 proved
// occupancy isn't binding): W staging bytes + barriers halve per row; LDS
// reads per FMA drop 25% (12 b128 / 128 FMA vs 8 / 64). LDS 44.8KB -> 3
// blocks/CU. GEMM k-loop unroll 2 (R14 VGPR-cliff lesson), cap 256x3.
__global__ __launch_bounds__(256, 3) void k_fuse(const float* __restrict__ h1,
    const int* __restrict__ row_ofs, const int* __restrict__ esrc,
    const int* __restrict__ sel1, const float* __restrict__ tgo,
    const float* __restrict__ W2r, const float* __restrict__ W2n,
    const float* __restrict__ b2, const float* __restrict__ p2,
    float* __restrict__ h2, float* __restrict__ score2,
    float* __restrict__ pmax, float* __restrict__ psum, int G8) {
  __shared__ float sW[32 * 64];      // 8 KB: [k_local][c]
  __shared__ float sG[128 * 68];     // 34.8 KB: agg then self (two phases)
  __shared__ float redm[4][64], reds[4][64];
  int b = blockIdx.x, s, tb;
  if (G8 > 0) { int hi = b >> 3; s = (b & 7) * G8 + hi / TBF; tb = hi % TBF; }
  else { s = b / TBF; tb = b % TBF; }
  int tid = threadIdx.x;
  int j0 = tb * 128;
  int nv = KK1 - j0; if (nv > 128) nv = 128;
  int r = tid >> 1, q = tid & 1;     // 2 threads/row, 32 floats each
  bool rv = r < nv;
  int d = 0;
  const float* H = h1 + (size_t)s * NN * HD;
  const float* TG = tgo + (size_t)s * NN;
  float td = 0.f;
  if (rv) {
    d = sel1[(size_t)s * KK1 + j0 + r];
    td = TG[d];
  }
  int rb = (tid >> 4) * 8;           // 16 row-groups x 8 rows
  int c0 = (tid & 15) * 4;
  float acc[8][4];
#pragma unroll
  for (int i = 0; i < 8; i++)
#pragma unroll
    for (int cc = 0; cc < 4; cc++) acc[i][cc] = 0.f;

#define STAGE_W(Wsrc, kbase)                                   \
  _Pragma("unroll 4")                                          \
  for (int i = tid; i < 32 * 64; i += 256) {                   \
    int k = i >> 6, c = i & 63;                                \
    sW[i] = (Wsrc)[c * 64 + (kbase) + k];                      \
  }
#define GEMM_SEG(gofs)                                         \
  _Pragma("unroll 2")                                          \
  for (int k = 0; k < 32; k += 4) {                            \
    float4 w0 = *(const float4*)&sW[(k + 0) * 64 + c0];        \
    float4 w1 = *(const float4*)&sW[(k + 1) * 64 + c0];        \
    float4 w2 = *(const float4*)&sW[(k + 2) * 64 + c0];        \
    float4 w3 = *(const float4*)&sW[(k + 3) * 64 + c0];        \
    _Pragma("unroll")                                          \
    for (int i = 0; i < 8; i++) {                              \
      float4 g = *(const float4*)&sG[(rb + i) * 68 + (gofs) + k]; \
      acc[i][0] += g.x * w0.x + g.y * w1.x + g.z * w2.x + g.w * w3.x; \
      acc[i][1] += g.x * w0.y + g.y * w1.y + g.z * w2.y + g.w * w3.y; \
      acc[i][2] += g.x * w0.z + g.y * w1.z + g.z * w2.z + g.w * w3.z; \
      acc[i][3] += g.x * w0.w + g.y * w1.w + g.z * w2.w + g.w * w3.w; \
    }                                                          \
  }

  // ---- phase 1: gather agg into sG + stage W2r-lo ----
  STAGE_W(W2r, 0)
  {
    float4 a0 = {0.f,0.f,0.f,0.f}, a1 = a0, a2 = a0, a3 = a0;
    float4 a4 = a0, a5 = a0, a6 = a0, a7 = a0;
    if (rv) {
      const int* RO = row_ofs + (size_t)s * (NN + 1);
      const int* ES = esrc + (size_t)s * EE;
      int e0 = RO[d], e1 = RO[d + 1];
      for (int e = e0; e < e1; e++) {
        int o = ES[e];
        float w = TG[o];
        const float4* ho = (const float4*)(H + (size_t)o * HD + q * 32);
        float4 v0 = ho[0], v1 = ho[1], v2 = ho[2], v3 = ho[3];
        float4 v4 = ho[4], v5 = ho[5], v6 = ho[6], v7 = ho[7];
        a0.x += w * v0.x; a0.y += w * v0.y; a0.z += w * v0.z; a0.w += w * v0.w;
        a1.x += w * v1.x; a1.y += w * v1.y; a1.z += w * v1.z; a1.w += w * v1.w;
        a2.x += w * v2.x; a2.y += w * v2.y; a2.z += w * v2.z; a2.w += w * v2.w;
        a3.x += w * v3.x; a3.y += w * v3.y; a3.z += w * v3.z; a3.w += w * v3.w;
        a4.x += w * v4.x; a4.y += w * v4.y; a4.z += w * v4.z; a4.w += w * v4.w;
        a5.x += w * v5.x; a5.y += w * v5.y; a5.z += w * v5.z; a5.w += w * v5.w;
        a6.x += w * v6.x; a6.y += w * v6.y; a6.z += w * v6.z; a6.w += w * v6.w;
        a7.x += w * v7.x; a7.y += w * v7.y; a7.z += w * v7.z; a7.w += w * v7.w;
      }
    }
    float* gw = &sG[r * 68 + q * 32];
    ((float4*)gw)[0] = a0; ((float4*)gw)[1] = a1;
    ((float4*)gw)[2] = a2; ((float4*)gw)[3] = a3;
    ((float4*)gw)[4] = a4; ((float4*)gw)[5] = a5;
    ((float4*)gw)[6] = a6; ((float4*)gw)[7] = a7;
  }
  __syncthreads();
  GEMM_SEG(0)           // agg x W2r k=0..31
  __syncthreads();
  STAGE_W(W2r, 32)
  __syncthreads();
  GEMM_SEG(32)          // agg x W2r k=32..63
  __syncthreads();
  // ---- restage self into sG + stage W2n-lo ----
  STAGE_W(W2n, 0)
  {
    float4 s0 = {0.f,0.f,0.f,0.f}, s1 = s0, s2 = s0, s3 = s0;
    float4 s4 = s0, s5 = s0, s6 = s0, s7 = s0;
    if (rv) {
      const float4* hd = (const float4*)(H + (size_t)d * HD + q * 32);
      s0 = hd[0]; s1 = hd[1]; s2 = hd[2]; s3 = hd[3];
      s4 = hd[4]; s5 = hd[5]; s6 = hd[6]; s7 = hd[7];
      s0.x *= td; s0.y *= td; s0.z *= td; s0.w *= td;
      s1.x *= td; s1.y *= td; s1.z *= td; s1.w *= td;
      s2.x *= td; s2.y *= td; s2.z *= td; s2.w *= td;
      s3.x *= td; s3.y *= td; s3.z *= td; s3.w *= td;
      s4.x *= td; s4.y *= td; s4.z *= td; s4.w *= td;
      s5.x *= td; s5.y *= td; s5.z *= td; s5.w *= td;
      s6.x *= td; s6.y *= td; s6.z *= td; s6.w *= td;
      s7.x *= td; s7.y *= td; s7.z *= td; s7.w *= td;
    }
    float* gs = &sG[r * 68 + q * 32];
    ((float4*)gs)[0] = s0; ((float4*)gs)[1] = s1;
    ((float4*)gs)[2] = s2; ((float4*)gs)[3] = s3;
    ((float4*)gs)[4] = s4; ((float4*)gs)[5] = s5;
    ((float4*)gs)[6] = s6; ((float4*)gs)[7] = s7;
  }
  __syncthreads();
  // read1 partials over 128 staged self rows (4 groups x 32 rows)
  {
    int c = tid & 63, qq = tid >> 6;
    float mx = -FLT_MAX, sm = 0.f;
    int rend = qq * 32 + 32; if (rend > nv) rend = nv;
    for (int rr = qq * 32; rr < rend; rr++) {
      float v = sG[rr * 68 + c];
      mx = fmaxf(mx, v); sm += v;
    }
    redm[qq][c] = mx; reds[qq][c] = sm;
  }
  GEMM_SEG(0)           // self x W2n k=0..31
  __syncthreads();
  STAGE_W(W2n, 32)
  if (tid < 64) {       // final read1 reduce overlaps W2n-hi stage
    float mx = redm[0][tid], sm = reds[0][tid];
    for (int qq = 1; qq < 4; qq++) { mx = fmaxf(mx, redm[qq][tid]); sm += reds[qq][tid]; }
    pmax[((size_t)s * TBF + tb) * 64 + tid] = mx;
    psum[((size_t)s * TBF + tb) * 64 + tid] = sm;
  }
  __syncthreads();
  GEMM_SEG(32)          // self x W2n k=32..63
#undef STAGE_W
#undef GEMM_SEG
  // ---- epilogue: bias + ReLU + h2 write + score2 ----
  float4 b2v = *(const float4*)&b2[c0];
  float4 p2v = *(const float4*)&p2[c0];
  float nq = p2v.x * p2v.x + p2v.y * p2v.y + p2v.z * p2v.z + p2v.w * p2v.w;
  nq += __shfl_xor(nq, 1, 64);
  nq += __shfl_xor(nq, 2, 64);
  nq += __shfl_xor(nq, 4, 64);
  nq += __shfl_xor(nq, 8, 64);
  float inv_norm = 1.0f / sqrtf(nq);
  float vs[8];
#pragma unroll
  for (int i = 0; i < 8; i++) {
    int j = j0 + rb + i;
    float4 h;
    h.x = fmaxf(acc[i][0] + b2v.x, 0.f);
    h.y = fmaxf(acc[i][1] + b2v.y, 0.f);
    h.z = fmaxf(acc[i][2] + b2v.z, 0.f);
    h.w = fmaxf(acc[i][3] + b2v.w, 0.f);
    if (j < KK1) *(float4*)&h2[((size_t)s * KK1 + j) * 64 + c0] = h;
    vs[i] = h.x * p2v.x + h.y * p2v.y + h.z * p2v.z + h.w * p2v.w;
  }
#pragma unroll
  for (int i = 0; i < 8; i++) {
    vs[i] += __shfl_xor(vs[i], 1, 64);
    vs[i] += __shfl_xor(vs[i], 2, 64);
    vs[i] += __shfl_xor(vs[i], 4, 64);
    vs[i] += __shfl_xor(vs[i], 8, 64);
  }
  if ((tid & 15) == 0) {
#pragma unroll
    for (int i = 0; i < 8; i++) {
      int j = j0 + rb + i;
      if (j < KK1) score2[(size_t)s * KK1 + j] = vs[i] * inv_norm;
    }
  }
}

// ---------- read2 partials: stream h2 rows, mask by pos2 --------------------
__global__ __launch_bounds__(256) void k_read2p(const float* __restrict__ h2,
    const int* __restrict__ pos2, const float* __restrict__ score2,
    float* __restrict__ p2max, float* __restrict__ p2sum) {
  int s = blockIdx.x / RB2, pb = blockIdx.x % RB2;
  int lane = threadIdx.x & 63, wave = threadIdx.x >> 6;
  const int ROWS = (KK1 + RB2 - 1) / RB2;  // 205
  int j0 = pb * ROWS;
  int j1 = j0 + ROWS; if (j1 > KK1) j1 = KK1;
  float mx = -FLT_MAX, sm = 0.f;
  for (int j = j0 + wave; j < j1; j += 4) {
    if (pos2[(size_t)s * KK1 + j] >= 0) {
      float t = tanhf(score2[(size_t)s * KK1 + j]);
      float v = h2[((size_t)s * KK1 + j) * HD + lane] * t;
      mx = fmaxf(mx, v); sm += v;
    }
  }
  __shared__ float smx[4][64], ssm[4][64];
  smx[wave][lane] = mx; ssm[wave][lane] = sm;
  __syncthreads();
  if (wave == 0) {
    for (int q = 1; q < 4; q++) { mx = fmaxf(mx, smx[q][lane]); sm += ssm[q][lane]; }
    p2max[((size_t)s * RB2 + pb) * 64 + lane] = mx;
    p2sum[((size_t)s * RB2 + pb) * 64 + lane] = sm;
  }
}

// ---------- merged final reduce: feats = read1 + read2 ----------------------
__global__ __launch_bounds__(64) void k_readf(const float* __restrict__ pmax,
    const float* __restrict__ psum, const float* __restrict__ p2max,
    const float* __restrict__ p2sum, float* __restrict__ feats, int g0) {
  int s = blockIdx.x, k = threadIdx.x;
  float mx1 = -FLT_MAX, sm1 = 0.f;
  for (int t = 0; t < TBF; t++) {
    mx1 = fmaxf(mx1, pmax[((size_t)s * TBF + t) * 64 + k]);
    sm1 += psum[((size_t)s * TBF + t) * 64 + k];
  }
  float mx2 = -FLT_MAX, sm2 = 0.f;
  for (int t = 0; t < RB2; t++) {
    mx2 = fmaxf(mx2, p2max[((size_t)s * RB2 + t) * 64 + k]);
    sm2 += p2sum[((size_t)s * RB2 + t) * 64 + k];
  }
  feats[(size_t)(g0 + s) * 128 + k] = mx1 + mx2;
  feats[(size_t)(g0 + s) * 128 + 64 + k] = sm1 / (float)KK1 + sm2 / (float)KK2;
}

// ---------- head A: per-graph MLP -> logits a5[64][10] ----------------------
__global__ __launch_bounds__(256) void k_heada(const float* __restrict__ feats,
    const float* __restrict__ Wa1, const float* __restrict__ ba1,
    const float* __restrict__ Wa5, const float* __restrict__ ba5,
    float* __restrict__ a5) {
  __shared__ float sF[128];
  __shared__ float sA1[64];
  int b = blockIdx.x, t = threadIdx.x;
  if (t < 32) ((float4*)sF)[t] = ((const float4*)(feats + (size_t)b * 128))[t];
  __syncthreads();
  {
    int j = t >> 2, q = t & 3;
    const float4* w = (const float4*)(Wa1 + (size_t)j * 128 + q * 32);
    const float4* f4 = (const float4*)(sF + q * 32);
    float acc = 0.f;
#pragma unroll
    for (int i = 0; i < 8; i++) {
      float4 wv = w[i], fv = f4[i];
      acc += wv.x * fv.x + wv.y * fv.y + wv.z * fv.z + wv.w * fv.w;
    }
    acc += __shfl_xor(acc, 1, 64);
    acc += __shfl_xor(acc, 2, 64);
    if (q == 0) sA1[j] = fmaxf(acc + ba1[j], 0.f);
  }
  __syncthreads();
  if (t < 160) {
    int c = t >> 4, l = t & 15;
    float acc = 0.f;
#pragma unroll
    for (int i = 0; i < 4; i++) {
      int jj = l * 4 + i;
      acc += sA1[jj] * Wa5[c * 64 + jj];
    }
    acc += __shfl_xor(acc, 1, 64);
    acc += __shfl_xor(acc, 2, 64);
    acc += __shfl_xor(acc, 4, 64);
    acc += __shfl_xor(acc, 8, 64);
    if (l == 0) a5[b * 10 + c] = acc + ba5[c];
  }
}

// ---------- head B: softmax across graphs (axis 0) --------------------------
__global__ __launch_bounds__(64) void k_headb(const float* __restrict__ a5,
    float* __restrict__ out) {
  int c = threadIdx.x;
  if (c < 10) {
    float m = -FLT_MAX;
    for (int b = 0; b < BB; b++) m = fmaxf(m, a5[b * 10 + c]);
    float sum = 0.f;
    for (int b = 0; b < BB; b++) sum += expf(a5[b * 10 + c] - m);
    float inv = 1.0f / sum;
    for (int b = 0; b < BB; b++) out[b * 10 + c] = expf(a5[b * 10 + c] - m) * inv;
  }
}

extern "C" void kernel_launch(void* const* d_in, const int* in_sizes, int n_in,
                              void* d_out, int out_size, void* d_ws, size_t ws_size,
                              hipStream_t stream) {
  const float* x   = (const float*)d_in[0];
  const int*   ei  = (const int*)d_in[1];
  const float* W1r = (const float*)d_in[2];
  const float* b1  = (const float*)d_in[3];
  const float* W1n = (const float*)d_in[4];
  const float* p1  = (const float*)d_in[5];
  const float* W2r = (const float*)d_in[6];
  const float* b2  = (const float*)d_in[7];
  const float* W2n = (const float*)d_in[8];
  const float* p2  = (const float*)d_in[9];
  const float* Wa1 = (const float*)d_in[10];
  const float* ba1 = (const float*)d_in[11];
  const float* Wa5 = (const float*)d_in[12];
  const float* ba5 = (const float*)d_in[13];
  float* out = (float*)d_out;

  char* base = (char*)d_ws;
  size_t off = 0;
  auto alloc = [&](size_t bytes) -> void* {
    void* p = base + off;
    off = (off + bytes + 255) & ~(size_t)255;
    return p;
  };
  float* feats = (float*)alloc((size_t)BB * 128 * 4);
  float* a5buf = (float*)alloc((size_t)BB * 10 * 4);

  const size_t perSlot =
      ((size_t)(NN + 1) + EE + (size_t)NN * HD + NN + KK1 + NN +
       (size_t)KK1 * HD + 2 * (size_t)KK1 +
       2 * (size_t)TBF * 64 + 2 * (size_t)RB2 * 64) * 4
      + 24 * 256;
  size_t avail = ws_size > off ? ws_size - off : 0;
  int CH = (int)(avail / perSlot);
  if (CH > BB) CH = BB;
  if (CH < 1) CH = 1;

  int*   row_ofs = (int*)alloc((size_t)CH * (NN + 1) * 4);
  int*   esrc    = (int*)alloc((size_t)CH * EE * 4);
  float* h1      = (float*)alloc((size_t)CH * NN * HD * 4);
  float* score1  = (float*)alloc((size_t)CH * NN * 4);
  int*   sel1    = (int*)alloc((size_t)CH * KK1 * 4);
  float* tgo     = (float*)alloc((size_t)CH * NN * 4);
  float* h2      = (float*)alloc((size_t)CH * KK1 * HD * 4);
  float* score2  = (float*)alloc((size_t)CH * KK1 * 4);
  int*   pos2    = (int*)alloc((size_t)CH * KK1 * 4);
  float* pmax    = (float*)alloc((size_t)CH * TBF * 64 * 4);
  float* psum    = (float*)alloc((size_t)CH * TBF * 64 * 4);
  float* p2max   = (float*)alloc((size_t)CH * RB2 * 64 * 4);
  float* p2sum   = (float*)alloc((size_t)CH * RB2 * 64 * 4);

  for (int g0 = 0; g0 < BB; g0 += CH) {
    int G = (BB - g0) < CH ? (BB - g0) : CH;
    int G8 = (G % 8 == 0) ? G / 8 : 0;
    k_csr<<<G, 1024, 0, stream>>>(ei, row_ofs, esrc, g0);
    k_h1f<<<G * 16, 256, 0, stream>>>(x, row_ofs, esrc, W1r, b1, W1n, p1, h1, score1, g0, G8);
    k_select<<<G, 1024, 0, stream>>>(score1, NN, NN, KK1, sel1, KK1, nullptr, 0, tgo);
    k_fuse<<<G * TBF, 256, 0, stream>>>(h1, row_ofs, esrc, sel1, tgo, W2r, W2n, b2, p2,
                                        h2, score2, pmax, psum, G8);
    k_select<<<G, 1024, 0, stream>>>(score2, KK1, KK1, KK2, nullptr, 0, pos2, KK1, nullptr);
    k_read2p<<<G * RB2, 256, 0, stream>>>(h2, pos2, score2, p2max, p2sum);
    k_readf<<<G, 64, 0, stream>>>(pmax, psum, p2max, p2sum, feats, g0);
  }
  k_heada<<<BB, 256, 0, stream>>>(feats, Wa1, ba1, Wa5, ba5, a5buf);
  k_headb<<<1, 64, 0, stream>>>(a5buf, out);
}

// Round 21
// 292.628 us; speedup vs baseline: 1.0511x; 1.0511x over previous
//
#include <hip/hip_runtime.h>
#include <float.h>
#include <math.h>

#define BB 64
#define NN 4096
#define EE 32768
#define FIN 12
#define HD 64
#define KK1 3277
#define KK2 2622
#define TB1 52    // ceil(KK1/64) -- row tiles per graph for k_fuse
#define RB2 16    // blocks per graph for read2 partials

// ---------- CSR build: per-graph counting sort of edges by dst --------------
__global__ __launch_bounds__(1024) void k_csr(const int* __restrict__ ei,
    int* __restrict__ row_ofs, int* __restrict__ esrc, int g0) {
  __shared__ int cnt[NN];
  __shared__ int part[1024];
  int s = blockIdx.x, g = g0 + s, t = threadIdx.x;
  const int* src = ei + (size_t)g * 2 * EE;
  const int* dst = src + EE;
  for (int i = t; i < NN; i += 1024) cnt[i] = 0;
  __syncthreads();
  for (int e = t; e < EE; e += 1024) atomicAdd(&cnt[dst[e]], 1);
  __syncthreads();
  int c0 = cnt[t * 4], c1 = cnt[t * 4 + 1], c2 = cnt[t * 4 + 2], c3 = cnt[t * 4 + 3];
  int tot = c0 + c1 + c2 + c3;
  part[t] = tot;
  __syncthreads();
  for (int off = 1; off < 1024; off <<= 1) {
    int v = part[t];
    int add = (t >= off) ? part[t - off] : 0;
    __syncthreads();
    part[t] = v + add;
    __syncthreads();
  }
  int base = part[t] - tot;
  int b0 = base, b1 = base + c0, b2 = b1 + c1, b3 = b2 + c2;
  cnt[t * 4] = b0; cnt[t * 4 + 1] = b1; cnt[t * 4 + 2] = b2; cnt[t * 4 + 3] = b3;
  int* RO = row_ofs + (size_t)s * (NN + 1);
  RO[t * 4] = b0; RO[t * 4 + 1] = b1; RO[t * 4 + 2] = b2; RO[t * 4 + 3] = b3;
  if (t == 0) RO[NN] = EE;
  __syncthreads();
  int* ES = esrc + (size_t)s * EE;
  for (int e = t; e < EE; e += 1024) {
    int p = atomicAdd(&cnt[dst[e]], 1);
    ES[p] = src[e];
  }
}

// ---------- fused conv1 v3: W/b/p wave-uniform from global (scalarized) -----
__global__ __launch_bounds__(256, 4) void k_h1f(const float* __restrict__ x,
    const int* __restrict__ row_ofs, const int* __restrict__ esrc,
    const float* __restrict__ W1r, const float* __restrict__ b1,
    const float* __restrict__ W1n, const float* __restrict__ p1,
    float* __restrict__ h1, float* __restrict__ score1, int g0, int G8) {
  __shared__ float sCol[32][257];
  int tid = threadIdx.x;
  int b = blockIdx.x, s, nb;
  if (G8 > 0) { int hi = b >> 3; s = (b & 7) * G8 + hi / 16; nb = hi % 16; }
  else { s = b >> 4; nb = b & 15; }
  int node = nb * 256 + tid;
  int g = g0 + s;
  float nq = 0.f;
#pragma unroll 8
  for (int k = 0; k < 64; k++) nq += p1[k] * p1[k];
  float inv_norm = 1.0f / sqrtf(nq);
  const int* RO = row_ofs + (size_t)s * (NN + 1);
  const int* ES = esrc + (size_t)s * EE;
  const float4* X4 = (const float4*)(x + (size_t)g * NN * FIN);
  int r0 = RO[node], r1 = RO[node + 1];
  float a[FIN];
#pragma unroll
  for (int f = 0; f < FIN; f++) a[f] = 0.f;
  for (int i = r0; i < r1; i++) {
    int so = ES[i];
    float4 v0 = X4[(size_t)so * 3];
    float4 v1 = X4[(size_t)so * 3 + 1];
    float4 v2 = X4[(size_t)so * 3 + 2];
    a[0] += v0.x; a[1] += v0.y; a[2]  += v0.z; a[3]  += v0.w;
    a[4] += v1.x; a[5] += v1.y; a[6]  += v1.z; a[7]  += v1.w;
    a[8] += v2.x; a[9] += v2.y; a[10] += v2.z; a[11] += v2.w;
  }
  float xr[FIN];
  {
    float4 u0 = X4[(size_t)node * 3];
    float4 u1 = X4[(size_t)node * 3 + 1];
    float4 u2 = X4[(size_t)node * 3 + 2];
    xr[0] = u0.x; xr[1] = u0.y; xr[2]  = u0.z; xr[3]  = u0.w;
    xr[4] = u1.x; xr[5] = u1.y; xr[6]  = u1.z; xr[7]  = u1.w;
    xr[8] = u2.x; xr[9] = u2.y; xr[10] = u2.z; xr[11] = u2.w;
  }
  float* hbase = h1 + ((size_t)s * NN + (size_t)nb * 256) * HD;
  float v = 0.f;
  for (int half = 0; half < 2; half++) {
#pragma unroll 4
    for (int k0 = 0; k0 < 32; k0++) {
      int k = half * 32 + k0;
      const float* wr = &W1r[k * FIN];   // wave-uniform -> s_load
      const float* wn = &W1n[k * FIN];
      float acc = b1[k];
#pragma unroll
      for (int f = 0; f < FIN; f++) acc += a[f] * wr[f] + xr[f] * wn[f];
      acc = fmaxf(acc, 0.f);
      v += acc * p1[k];
      sCol[k0][tid] = acc;
    }
    __syncthreads();
    float* hb = hbase + half * 32;
    for (int i = tid; i < 256 * 32; i += 256) {
      int nd = i >> 5, c = i & 31;
      hb[(size_t)nd * HD + c] = sCol[c][nd];
    }
    __syncthreads();
  }
  score1[(size_t)s * NN + node] = v * inv_norm;
}

// ---------- top-k select via RADIX-SELECT (exact jax.lax.top_k SET) ---------
// Stage 1 (tgo!=nullptr): tgo[i]=tanh(score) if kept else 0, pos gets rank.
// Stage 2 (sel==nullptr): pos is only used as a >=0 flag -> skip rank scan.
__global__ __launch_bounds__(1024) void k_select(const float* __restrict__ score,
    int scStride, int nvalid, int K, int* __restrict__ sel, int selStride,
    int* __restrict__ pos, int posStride, float* __restrict__ tgo) {
  __shared__ unsigned int keys[4096];
  __shared__ int hist[257];
  __shared__ int part[1024];
  __shared__ unsigned int sh_pref;
  __shared__ int sh_rem;
  int s = blockIdx.x, t = threadIdx.x;
  const float* sc = score + (size_t)s * scStride;
  for (int i = t; i < 4096; i += 1024) {
    unsigned int key = 0u;
    if (i < nvalid) {
      unsigned int bb = __float_as_uint(sc[i]);
      key = (bb & 0x80000000u) ? ~bb : (bb | 0x80000000u);  // order-preserving
    }
    keys[i] = key;
  }
  if (t == 0) { sh_pref = 0u; sh_rem = K; }
  __syncthreads();
  for (int sh = 24; sh >= 0; sh -= 8) {
    unsigned int pref = sh_pref;
    int rem = sh_rem;
    if (t < 256) hist[t] = 0;
    __syncthreads();
    for (int i = t; i < 4096; i += 1024) {
      unsigned int u = keys[i];
      bool in = (sh == 24) || ((u >> (sh + 8)) == pref);
      if (in) atomicAdd(&hist[(u >> sh) & 255], 1);
    }
    __syncthreads();
    for (int off = 1; off < 256; off <<= 1) {
      int v = 0;
      if (t < 256) { v = hist[t]; if (t + off < 256) v += hist[t + off]; }
      __syncthreads();
      if (t < 256) hist[t] = v;
      __syncthreads();
    }
    if (t < 256) {
      int ge = hist[t];
      int gt_ = (t == 255) ? 0 : hist[t + 1];
      if (ge >= rem && gt_ < rem) {
        sh_pref = (pref << 8) | (unsigned int)t;
        sh_rem = rem - gt_;
      }
    }
    __syncthreads();
  }
  unsigned int thr = sh_pref;
  int remEq = sh_rem;
  uint4 kk = *(const uint4*)&keys[4 * t];
  int eq0 = (kk.x == thr), eq1 = (kk.y == thr), eq2 = (kk.z == thr), eq3 = (kk.w == thr);
  int eqc = eq0 + eq1 + eq2 + eq3;
  part[t] = eqc;
  __syncthreads();
  for (int off = 1; off < 1024; off <<= 1) {
    int v = part[t];
    int add = (t >= off) ? part[t - off] : 0;
    __syncthreads();
    part[t] = v + add;
    __syncthreads();
  }
  int e_run = part[t] - eqc;
  int kp0 = (kk.x > thr) || (eq0 && (e_run < remEq)); e_run += eq0;
  int kp1 = (kk.y > thr) || (eq1 && (e_run < remEq)); e_run += eq1;
  int kp2 = (kk.z > thr) || (eq2 && (e_run < remEq)); e_run += eq2;
  int kp3 = (kk.w > thr) || (eq3 && (e_run < remEq));
  int kp[4] = {kp0, kp1, kp2, kp3};
  if (sel) {   // need ranks: second scan
    int kc = kp0 + kp1 + kp2 + kp3;
    __syncthreads();
    part[t] = kc;
    __syncthreads();
    for (int off = 1; off < 1024; off <<= 1) {
      int v = part[t];
      int add = (t >= off) ? part[t - off] : 0;
      __syncthreads();
      part[t] = v + add;
      __syncthreads();
    }
    int r = part[t] - kc;
#pragma unroll
    for (int q = 0; q < 4; q++) {
      int i = 4 * t + q;
      if (i < nvalid) {
        if (kp[q]) {
          sel[(size_t)s * selStride + r] = i;
          if (pos) pos[(size_t)s * posStride + i] = r;
          if (tgo) tgo[(size_t)s * NN + i] = tanhf(sc[i]);
        } else {
          if (pos) pos[(size_t)s * posStride + i] = -1;
          if (tgo) tgo[(size_t)s * NN + i] = 0.f;
        }
      }
      r += kp[q];
    }
  } else {     // flag-only fast path (stage 2)
#pragma unroll
    for (int q = 0; q < 4; q++) {
      int i = 4 * t + q;
      if (i < nvalid) {
        if (pos) pos[(size_t)s * posStride + i] = kp[q] ? 0 : -1;
        if (tgo) tgo[(size_t)s * NN + i] = kp[q] ? tanhf(sc[i]) : 0.f;
      }
    }
  }
}

// ---------- k_fuse v6 (session champion): k-split W staging, 5 blocks/CU ----
// LDS 27.6KB (sW[32][64]=8K + sG[64][68]=17.4K + red 2K). W staged in 4
// chunks (W2r lo/hi, W2n lo/hi); GEMM runs in 4 segments into the same acc.
// read1-partials reduce overlaps the W2n-hi stage. Unrolls hand-bounded.
// R20 note: six k_fuse architectures all land 140-166us; this is the best.
__global__ __launch_bounds__(256, 5) void k_fuse(const float* __restrict__ h1,
    const int* __restrict__ row_ofs, const int* __restrict__ esrc,
    const int* __restrict__ sel1, const float* __restrict__ tgo,
    const float* __restrict__ W2r, const float* __restrict__ W2n,
    const float* __restrict__ b2, const float* __restrict__ p2,
    float* __restrict__ h2, float* __restrict__ score2,
    float* __restrict__ pmax, float* __restrict__ psum, int G8) {
  __shared__ float sW[32 * 64];     // 8 KB: [k_local][c]
  __shared__ float sG[64 * 68];     // 17.4 KB: agg half then self half
  __shared__ float redm[4][64], reds[4][64];
  int b = blockIdx.x, s, tb;
  if (G8 > 0) { int hi = b >> 3; s = (b & 7) * G8 + hi / TB1; tb = hi % TB1; }
  else { s = b / TB1; tb = b % TB1; }
  int tid = threadIdx.x;
  int j0 = tb * 64;
  int nv = KK1 - j0; if (nv > 64) nv = 64;
  int r = tid >> 2, q = tid & 3;
  bool rv = r < nv;
  int d = 0;
  const float* H = h1 + (size_t)s * NN * HD;
  const float* TG = tgo + (size_t)s * NN;
  float td = 0.f;
  if (rv) {
    d = sel1[(size_t)s * KK1 + j0 + r];
    td = TG[d];
  }
  int rb = (tid >> 4) * 4;
  int c0 = (tid & 15) * 4;
  float acc[4][4];
#pragma unroll
  for (int i = 0; i < 4; i++)
#pragma unroll
    for (int cc = 0; cc < 4; cc++) acc[i][cc] = 0.f;

#define STAGE_W(Wsrc, kbase)                                   \
  _Pragma("unroll 4")                                          \
  for (int i = tid; i < 32 * 64; i += 256) {                   \
    int k = i >> 6, c = i & 63;                                \
    sW[i] = (Wsrc)[c * 64 + (kbase) + k];                      \
  }
#define GEMM_SEG(gofs)                                         \
  _Pragma("unroll 4")                                          \
  for (int k = 0; k < 32; k += 4) {                            \
    float4 w0 = *(const float4*)&sW[(k + 0) * 64 + c0];        \
    float4 w1 = *(const float4*)&sW[(k + 1) * 64 + c0];        \
    float4 w2 = *(const float4*)&sW[(k + 2) * 64 + c0];        \
    float4 w3 = *(const float4*)&sW[(k + 3) * 64 + c0];        \
    _Pragma("unroll")                                          \
    for (int i = 0; i < 4; i++) {                              \
      float4 g = *(const float4*)&sG[(rb + i) * 68 + (gofs) + k]; \
      acc[i][0] += g.x * w0.x + g.y * w1.x + g.z * w2.x + g.w * w3.x; \
      acc[i][1] += g.x * w0.y + g.y * w1.y + g.z * w2.y + g.w * w3.y; \
      acc[i][2] += g.x * w0.z + g.y * w1.z + g.z * w2.z + g.w * w3.z; \
      acc[i][3] += g.x * w0.w + g.y * w1.w + g.z * w2.w + g.w * w3.w; \
    }                                                          \
  }

  // ---- phase 1: gather agg into sG + stage W2r-lo ----
  STAGE_W(W2r, 0)
  {
    float4 a0 = {0.f,0.f,0.f,0.f}, a1 = a0, a2 = a0, a3 = a0;
    float4 b0 = a0, b1 = a0, b2v_ = a0, b3 = a0;
    if (rv) {
      const int* RO = row_ofs + (size_t)s * (NN + 1);
      const int* ES = esrc + (size_t)s * EE;
      int e0 = RO[d], e1 = RO[d + 1];
      int e = e0;
      for (; e + 2 <= e1; e += 2) {
        int oA = ES[e], oB = ES[e + 1];
        float wA = TG[oA], wB = TG[oB];
        const float4* hA = (const float4*)(H + (size_t)oA * HD + q * 16);
        const float4* hB = (const float4*)(H + (size_t)oB * HD + q * 16);
        float4 vA0 = hA[0], vA1 = hA[1], vA2 = hA[2], vA3 = hA[3];
        float4 vB0 = hB[0], vB1 = hB[1], vB2 = hB[2], vB3 = hB[3];
        a0.x += wA * vA0.x; a0.y += wA * vA0.y; a0.z += wA * vA0.z; a0.w += wA * vA0.w;
        a1.x += wA * vA1.x; a1.y += wA * vA1.y; a1.z += wA * vA1.z; a1.w += wA * vA1.w;
        a2.x += wA * vA2.x; a2.y += wA * vA2.y; a2.z += wA * vA2.z; a2.w += wA * vA2.w;
        a3.x += wA * vA3.x; a3.y += wA * vA3.y; a3.z += wA * vA3.z; a3.w += wA * vA3.w;
        b0.x += wB * vB0.x; b0.y += wB * vB0.y; b0.z += wB * vB0.z; b0.w += wB * vB0.w;
        b1.x += wB * vB1.x; b1.y += wB * vB1.y; b1.z += wB * vB1.z; b1.w += wB * vB1.w;
        b2v_.x += wB * vB2.x; b2v_.y += wB * vB2.y; b2v_.z += wB * vB2.z; b2v_.w += wB * vB2.w;
        b3.x += wB * vB3.x; b3.y += wB * vB3.y; b3.z += wB * vB3.z; b3.w += wB * vB3.w;
      }
      if (e < e1) {
        int o = ES[e];
        float w = TG[o];
        const float4* ho = (const float4*)(H + (size_t)o * HD + q * 16);
        float4 v0 = ho[0], v1 = ho[1], v2 = ho[2], v3 = ho[3];
        a0.x += w * v0.x; a0.y += w * v0.y; a0.z += w * v0.z; a0.w += w * v0.w;
        a1.x += w * v1.x; a1.y += w * v1.y; a1.z += w * v1.z; a1.w += w * v1.w;
        a2.x += w * v2.x; a2.y += w * v2.y; a2.z += w * v2.z; a2.w += w * v2.w;
        a3.x += w * v3.x; a3.y += w * v3.y; a3.z += w * v3.z; a3.w += w * v3.w;
      }
      a0.x += b0.x; a0.y += b0.y; a0.z += b0.z; a0.w += b0.w;
      a1.x += b1.x; a1.y += b1.y; a1.z += b1.z; a1.w += b1.w;
      a2.x += b2v_.x; a2.y += b2v_.y; a2.z += b2v_.z; a2.w += b2v_.w;
      a3.x += b3.x; a3.y += b3.y; a3.z += b3.z; a3.w += b3.w;
    }
    float* gw = &sG[r * 68 + q * 16];
    ((float4*)gw)[0] = a0; ((float4*)gw)[1] = a1;
    ((float4*)gw)[2] = a2; ((float4*)gw)[3] = a3;
  }
  __syncthreads();
  GEMM_SEG(0)           // agg x W2r k=0..31
  __syncthreads();
  STAGE_W(W2r, 32)
  __syncthreads();
  GEMM_SEG(32)          // agg x W2r k=32..63
  __syncthreads();
  // ---- restage self into sG + stage W2n-lo ----
  STAGE_W(W2n, 0)
  {
    float4 s0 = {0.f,0.f,0.f,0.f}, s1 = s0, s2 = s0, s3 = s0;
    if (rv) {
      const float4* hd = (const float4*)(H + (size_t)d * HD + q * 16);
      s0 = hd[0]; s1 = hd[1]; s2 = hd[2]; s3 = hd[3];
      s0.x *= td; s0.y *= td; s0.z *= td; s0.w *= td;
      s1.x *= td; s1.y *= td; s1.z *= td; s1.w *= td;
      s2.x *= td; s2.y *= td; s2.z *= td; s2.w *= td;
      s3.x *= td; s3.y *= td; s3.z *= td; s3.w *= td;
    }
    float* gs = &sG[r * 68 + q * 16];
    ((float4*)gs)[0] = s0; ((float4*)gs)[1] = s1;
    ((float4*)gs)[2] = s2; ((float4*)gs)[3] = s3;
  }
  __syncthreads();
  // read1 partials (reads self half just staged)
  {
    int c = tid & 63, qq = tid >> 6;
    float mx = -FLT_MAX, sm = 0.f;
    int rend = qq * 16 + 16; if (rend > nv) rend = nv;
    for (int rr = qq * 16; rr < rend; rr++) {
      float v = sG[rr * 68 + c];
      mx = fmaxf(mx, v); sm += v;
    }
    redm[qq][c] = mx; reds[qq][c] = sm;
  }
  GEMM_SEG(0)           // self x W2n k=0..31
  __syncthreads();
  STAGE_W(W2n, 32)
  // final read1 reduce overlaps the W2n-hi stage (redm complete pre-barrier)
  if (tid < 64) {
    float mx = redm[0][tid], sm = reds[0][tid];
    for (int qq = 1; qq < 4; qq++) { mx = fmaxf(mx, redm[qq][tid]); sm += reds[qq][tid]; }
    pmax[((size_t)s * TB1 + tb) * 64 + tid] = mx;
    psum[((size_t)s * TB1 + tb) * 64 + tid] = sm;
  }
  __syncthreads();
  GEMM_SEG(32)          // self x W2n k=32..63
#undef STAGE_W
#undef GEMM_SEG
  // ---- epilogue: bias + ReLU + h2 write + score2 ----
  float4 b2v = *(const float4*)&b2[c0];
  float4 p2v = *(const float4*)&p2[c0];
  float nq = p2v.x * p2v.x + p2v.y * p2v.y + p2v.z * p2v.z + p2v.w * p2v.w;
  nq += __shfl_xor(nq, 1, 64);
  nq += __shfl_xor(nq, 2, 64);
  nq += __shfl_xor(nq, 4, 64);
  nq += __shfl_xor(nq, 8, 64);
  float inv_norm = 1.0f / sqrtf(nq);
  float vs[4];
#pragma unroll
  for (int i = 0; i < 4; i++) {
    int j = j0 + rb + i;
    float4 h;
    h.x = fmaxf(acc[i][0] + b2v.x, 0.f);
    h.y = fmaxf(acc[i][1] + b2v.y, 0.f);
    h.z = fmaxf(acc[i][2] + b2v.z, 0.f);
    h.w = fmaxf(acc[i][3] + b2v.w, 0.f);
    if (j < KK1) *(float4*)&h2[((size_t)s * KK1 + j) * 64 + c0] = h;
    vs[i] = h.x * p2v.x + h.y * p2v.y + h.z * p2v.z + h.w * p2v.w;
  }
#pragma unroll
  for (int i = 0; i < 4; i++) {
    vs[i] += __shfl_xor(vs[i], 1, 64);
    vs[i] += __shfl_xor(vs[i], 2, 64);
    vs[i] += __shfl_xor(vs[i], 4, 64);
    vs[i] += __shfl_xor(vs[i], 8, 64);
  }
  if ((tid & 15) == 0) {
#pragma unroll
    for (int i = 0; i < 4; i++) {
      int j = j0 + rb + i;
      if (j < KK1) score2[(size_t)s * KK1 + j] = vs[i] * inv_norm;
    }
  }
}

// ---------- read2 partials: stream h2 rows, mask by pos2 --------------------
__global__ __launch_bounds__(256) void k_read2p(const float* __restrict__ h2,
    const int* __restrict__ pos2, const float* __restrict__ score2,
    float* __restrict__ p2max, float* __restrict__ p2sum) {
  int s = blockIdx.x / RB2, pb = blockIdx.x % RB2;
  int lane = threadIdx.x & 63, wave = threadIdx.x >> 6;
  const int ROWS = (KK1 + RB2 - 1) / RB2;  // 205
  int j0 = pb * ROWS;
  int j1 = j0 + ROWS; if (j1 > KK1) j1 = KK1;
  float mx = -FLT_MAX, sm = 0.f;
  for (int j = j0 + wave; j < j1; j += 4) {
    if (pos2[(size_t)s * KK1 + j] >= 0) {
      float t = tanhf(score2[(size_t)s * KK1 + j]);
      float v = h2[((size_t)s * KK1 + j) * HD + lane] * t;
      mx = fmaxf(mx, v); sm += v;
    }
  }
  __shared__ float smx[4][64], ssm[4][64];
  smx[wave][lane] = mx; ssm[wave][lane] = sm;
  __syncthreads();
  if (wave == 0) {
    for (int q = 1; q < 4; q++) { mx = fmaxf(mx, smx[q][lane]); sm += ssm[q][lane]; }
    p2max[((size_t)s * RB2 + pb) * 64 + lane] = mx;
    p2sum[((size_t)s * RB2 + pb) * 64 + lane] = sm;
  }
}

// ---------- merged final reduce: feats = read1 + read2 ----------------------
__global__ __launch_bounds__(64) void k_readf(const float* __restrict__ pmax,
    const float* __restrict__ psum, const float* __restrict__ p2max,
    const float* __restrict__ p2sum, float* __restrict__ feats, int g0) {
  int s = blockIdx.x, k = threadIdx.x;
  float mx1 = -FLT_MAX, sm1 = 0.f;
  for (int t = 0; t < TB1; t++) {
    mx1 = fmaxf(mx1, pmax[((size_t)s * TB1 + t) * 64 + k]);
    sm1 += psum[((size_t)s * TB1 + t) * 64 + k];
  }
  float mx2 = -FLT_MAX, sm2 = 0.f;
  for (int t = 0; t < RB2; t++) {
    mx2 = fmaxf(mx2, p2max[((size_t)s * RB2 + t) * 64 + k]);
    sm2 += p2sum[((size_t)s * RB2 + t) * 64 + k];
  }
  feats[(size_t)(g0 + s) * 128 + k] = mx1 + mx2;
  feats[(size_t)(g0 + s) * 128 + 64 + k] = sm1 / (float)KK1 + sm2 / (float)KK2;
}

// ---------- head A: per-graph MLP -> logits a5[64][10] ----------------------
__global__ __launch_bounds__(256) void k_heada(const float* __restrict__ feats,
    const float* __restrict__ Wa1, const float* __restrict__ ba1,
    const float* __restrict__ Wa5, const float* __restrict__ ba5,
    float* __restrict__ a5) {
  __shared__ float sF[128];
  __shared__ float sA1[64];
  int b = blockIdx.x, t = threadIdx.x;
  if (t < 32) ((float4*)sF)[t] = ((const float4*)(feats + (size_t)b * 128))[t];
  __syncthreads();
  {
    int j = t >> 2, q = t & 3;
    const float4* w = (const float4*)(Wa1 + (size_t)j * 128 + q * 32);
    const float4* f4 = (const float4*)(sF + q * 32);
    float acc = 0.f;
#pragma unroll
    for (int i = 0; i < 8; i++) {
      float4 wv = w[i], fv = f4[i];
      acc += wv.x * fv.x + wv.y * fv.y + wv.z * fv.z + wv.w * fv.w;
    }
    acc += __shfl_xor(acc, 1, 64);
    acc += __shfl_xor(acc, 2, 64);
    if (q == 0) sA1[j] = fmaxf(acc + ba1[j], 0.f);
  }
  __syncthreads();
  if (t < 160) {
    int c = t >> 4, l = t & 15;
    float acc = 0.f;
#pragma unroll
    for (int i = 0; i < 4; i++) {
      int jj = l * 4 + i;
      acc += sA1[jj] * Wa5[c * 64 + jj];
    }
    acc += __shfl_xor(acc, 1, 64);
    acc += __shfl_xor(acc, 2, 64);
    acc += __shfl_xor(acc, 4, 64);
    acc += __shfl_xor(acc, 8, 64);
    if (l == 0) a5[b * 10 + c] = acc + ba5[c];
  }
}

// ---------- head B: softmax across graphs (axis 0) --------------------------
__global__ __launch_bounds__(64) void k_headb(const float* __restrict__ a5,
    float* __restrict__ out) {
  int c = threadIdx.x;
  if (c < 10) {
    float m = -FLT_MAX;
    for (int b = 0; b < BB; b++) m = fmaxf(m, a5[b * 10 + c]);
    float sum = 0.f;
    for (int b = 0; b < BB; b++) sum += expf(a5[b * 10 + c] - m);
    float inv = 1.0f / sum;
    for (int b = 0; b < BB; b++) out[b * 10 + c] = expf(a5[b * 10 + c] - m) * inv;
  }
}

extern "C" void kernel_launch(void* const* d_in, const int* in_sizes, int n_in,
                              void* d_out, int out_size, void* d_ws, size_t ws_size,
                              hipStream_t stream) {
  const float* x   = (const float*)d_in[0];
  const int*   ei  = (const int*)d_in[1];
  const float* W1r = (const float*)d_in[2];
  const float* b1  = (const float*)d_in[3];
  const float* W1n = (const float*)d_in[4];
  const float* p1  = (const float*)d_in[5];
  const float* W2r = (const float*)d_in[6];
  const float* b2  = (const float*)d_in[7];
  const float* W2n = (const float*)d_in[8];
  const float* p2  = (const float*)d_in[9];
  const float* Wa1 = (const float*)d_in[10];
  const float* ba1 = (const float*)d_in[11];
  const float* Wa5 = (const float*)d_in[12];
  const float* ba5 = (const float*)d_in[13];
  float* out = (float*)d_out;

  char* base = (char*)d_ws;
  size_t off = 0;
  auto alloc = [&](size_t bytes) -> void* {
    void* p = base + off;
    off = (off + bytes + 255) & ~(size_t)255;
    return p;
  };
  float* feats = (float*)alloc((size_t)BB * 128 * 4);
  float* a5buf = (float*)alloc((size_t)BB * 10 * 4);

  const size_t perSlot =
      ((size_t)(NN + 1) + EE + (size_t)NN * HD + NN + KK1 + NN +
       (size_t)KK1 * HD + 2 * (size_t)KK1 +
       2 * (size_t)TB1 * 64 + 2 * (size_t)RB2 * 64) * 4
      + 24 * 256;
  size_t avail = ws_size > off ? ws_size - off : 0;
  int CH = (int)(avail / perSlot);
  if (CH > BB) CH = BB;
  if (CH < 1) CH = 1;

  int*   row_ofs = (int*)alloc((size_t)CH * (NN + 1) * 4);
  int*   esrc    = (int*)alloc((size_t)CH * EE * 4);
  float* h1      = (float*)alloc((size_t)CH * NN * HD * 4);
  float* score1  = (float*)alloc((size_t)CH * NN * 4);
  int*   sel1    = (int*)alloc((size_t)CH * KK1 * 4);
  float* tgo     = (float*)alloc((size_t)CH * NN * 4);
  float* h2      = (float*)alloc((size_t)CH * KK1 * HD * 4);
  float* score2  = (float*)alloc((size_t)CH * KK1 * 4);
  int*   pos2    = (int*)alloc((size_t)CH * KK1 * 4);
  float* pmax    = (float*)alloc((size_t)CH * TB1 * 64 * 4);
  float* psum    = (float*)alloc((size_t)CH * TB1 * 64 * 4);
  float* p2max   = (float*)alloc((size_t)CH * RB2 * 64 * 4);
  float* p2sum   = (float*)alloc((size_t)CH * RB2 * 64 * 4);

  for (int g0 = 0; g0 < BB; g0 += CH) {
    int G = (BB - g0) < CH ? (BB - g0) : CH;
    int G8 = (G % 8 == 0) ? G / 8 : 0;
    k_csr<<<G, 1024, 0, stream>>>(ei, row_ofs, esrc, g0);
    k_h1f<<<G * 16, 256, 0, stream>>>(x, row_ofs, esrc, W1r, b1, W1n, p1, h1, score1, g0, G8);
    k_select<<<G, 1024, 0, stream>>>(score1, NN, NN, KK1, sel1, KK1, nullptr, 0, tgo);
    k_fuse<<<G * TB1, 256, 0, stream>>>(h1, row_ofs, esrc, sel1, tgo, W2r, W2n, b2, p2,
                                        h2, score2, pmax, psum, G8);
    k_select<<<G, 1024, 0, stream>>>(score2, KK1, KK1, KK2, nullptr, 0, pos2, KK1, nullptr);
    k_read2p<<<G * RB2, 256, 0, stream>>>(h2, pos2, score2, p2max, p2sum);
    k_readf<<<G, 64, 0, stream>>>(pmax, psum, p2max, p2sum, feats, g0);
  }
  k_heada<<<BB, 256, 0, stream>>>(feats, Wa1, ba1, Wa5, ba5, a5buf);
  k_headb<<<1, 64, 0, stream>>>(a5buf, out);
}